// Round 1
// baseline (552.382 us; speedup 1.0000x reference)
//
#include <hip/hip_runtime.h>
#include <hip/hip_bf16.h>
#include <cstdint>

typedef unsigned short u16;
typedef __attribute__((ext_vector_type(8))) short short8;   // 8 bf16 = 4 VGPRs (MFMA A/B frag)
typedef __attribute__((ext_vector_type(4))) float f32x4;    // MFMA C/D frag

// round-to-nearest-even fp32 -> bf16 bits (inputs are finite normals; no NaN path needed)
__device__ __forceinline__ u16 f2bf(float f) {
  unsigned u = __float_as_uint(f);
  u += 0x7fffu + ((u >> 16) & 1u);
  return (u16)(u >> 16);
}

// ---- kernel 1: x = inputs / ||inputs||  (fp32 -> bf16), one block per row ----
__global__ void norm_cast_kernel(const float* __restrict__ in, u16* __restrict__ xb) {
  const int row = blockIdx.x;
  const int t = threadIdx.x;           // 256 threads, D = 256
  float v = in[row * 256 + t];
  float s = v * v;
  #pragma unroll
  for (int off = 32; off >= 1; off >>= 1) s += __shfl_xor(s, off, 64);
  __shared__ float wsum[4];
  if ((t & 63) == 0) wsum[t >> 6] = s;
  __syncthreads();
  const float tot = wsum[0] + wsum[1] + wsum[2] + wsum[3];
  xb[row * 256 + t] = f2bf(v * rsqrtf(tot));
}

// ---- kernel 2: features fp32 -> bf16 bank in workspace ----
__global__ void cvt_bf16_kernel(const float4* __restrict__ in, ushort4* __restrict__ out, int n4) {
  const int i = blockIdx.x * 256 + threadIdx.x;
  if (i < n4) {
    float4 v = in[i];
    out[i] = make_ushort4(f2bf(v.x), f2bf(v.y), f2bf(v.z), f2bf(v.w));
  }
}

// ---- kernel 3: C[M,N] = (X[M,K] . F[N,K]^T) * 20, bf16 MFMA, m97 structure ----
// BM=BN=128, BK=32, 256 threads = 4 waves in 2x2, each wave 4x4 of 16x16x32 MFMAs.
template <bool CONVB>
__global__ __launch_bounds__(256) void gemm_kernel(
    const u16* __restrict__ A,      // x bf16 [1024][256]
    const u16* __restrict__ Bbf,    // features bf16 [N][256]   (CONVB == false)
    const float* __restrict__ Bfp,  // features fp32 [N][256]   (CONVB == true)
    float* __restrict__ C, int Nn)
{
  __shared__ u16 As[128 * 32];   // 8 KB, row-major [row][k], contiguous (global_load_lds order)
  __shared__ u16 Bs[128 * 32];   // 8 KB

  const int tid  = threadIdx.x;
  const int wave = tid >> 6;
  const int lane = tid & 63;
  const int m0 = blockIdx.x * 128;       // grid.x = 8 (fast index -> feature-tile reuse in L2/L3)
  const int n0 = blockIdx.y * 128;
  const int wm = (wave & 1) * 64;
  const int wn = (wave >> 1) * 64;

  f32x4 acc[4][4] = {};

  // staging lane mapping: lane loads 16 B; 64 lanes cover 16 rows (4 chunks/row of 8 bf16)
  const int srow   = tid >> 2;           // 0..63 row within a 64-row half
  const int schunk = (tid & 3) * 8;      // k element offset

  for (int k0 = 0; k0 < 256; k0 += 32) {
    // ---- stage A: 128 rows x 32 k, two wave-rounds ----
    #pragma unroll
    for (int r = 0; r < 2; ++r) {
      const u16* gp = A + (size_t)(m0 + r * 64 + srow) * 256 + k0 + schunk;
      u16* lp = (u16*)As + (r * 4 + wave) * 512;   // wave-uniform; HW adds lane*16 B
      __builtin_amdgcn_global_load_lds(
          (const __attribute__((address_space(1))) void*)gp,
          (__attribute__((address_space(3))) void*)lp, 16, 0, 0);
    }
    // ---- stage B ----
    if constexpr (!CONVB) {
      #pragma unroll
      for (int r = 0; r < 2; ++r) {
        int grow = n0 + r * 64 + srow;
        if (grow >= Nn) grow = Nn - 1;             // clamp tail; unused at store
        const u16* gp = Bbf + (size_t)grow * 256 + k0 + schunk;
        u16* lp = (u16*)Bs + (r * 4 + wave) * 512;
        __builtin_amdgcn_global_load_lds(
            (const __attribute__((address_space(1))) void*)gp,
            (__attribute__((address_space(3))) void*)lp, 16, 0, 0);
      }
    } else {
      // on-the-fly fp32 -> bf16: 1024 float4 chunks, 4 rounds of 256
      #pragma unroll
      for (int r = 0; r < 4; ++r) {
        const int idx = r * 256 + tid;
        const int row = idx >> 3;
        const int kc  = (idx & 7) * 4;
        int grow = n0 + row;
        if (grow >= Nn) grow = Nn - 1;
        float4 v = *(const float4*)(Bfp + (size_t)grow * 256 + k0 + kc);
        *(ushort4*)(&Bs[row * 32 + kc]) =
            make_ushort4(f2bf(v.x), f2bf(v.y), f2bf(v.z), f2bf(v.w));
      }
    }
    __syncthreads();   // compiler emits s_waitcnt vmcnt(0) lgkmcnt(0) before s_barrier

    // ---- fragments + MFMA ----
    const int fr = lane & 15;            // frag row (m for A, n for B)
    const int kc = (lane >> 4) * 8;      // frag k chunk
    short8 af[4], bfr[4];
    #pragma unroll
    for (int i = 0; i < 4; ++i) {
      af[i]  = *(const short8*)(&As[(wm + i * 16 + fr) * 32 + kc]);
      bfr[i] = *(const short8*)(&Bs[(wn + i * 16 + fr) * 32 + kc]);
    }
    #pragma unroll
    for (int mi = 0; mi < 4; ++mi)
      #pragma unroll
      for (int ni = 0; ni < 4; ++ni)
        acc[mi][ni] = __builtin_amdgcn_mfma_f32_16x16x32_bf16(af[mi], bfr[ni], acc[mi][ni], 0, 0, 0);
    __syncthreads();
  }

  // ---- epilogue: C/D layout col=lane&15, row=(lane>>4)*4+reg ----
  const int col   = lane & 15;
  const int rquad = (lane >> 4) * 4;
  #pragma unroll
  for (int mi = 0; mi < 4; ++mi) {
    const int m = m0 + wm + mi * 16 + rquad;
    #pragma unroll
    for (int ni = 0; ni < 4; ++ni) {
      const int n = n0 + wn + ni * 16 + col;
      if (n < Nn) {
        float* cp = C + (size_t)m * Nn + n;
        #pragma unroll
        for (int i = 0; i < 4; ++i)
          cp[(size_t)i * Nn] = acc[mi][ni][i] * 20.0f;   // 1/TEMP
      }
    }
  }
}

extern "C" void kernel_launch(void* const* d_in, const int* in_sizes, int n_in,
                              void* d_out, int out_size, void* d_ws, size_t ws_size,
                              hipStream_t stream) {
  const float* inputs   = (const float*)d_in[0];
  // d_in[1] (targets) is dead code for the forward output
  const float* features = (const float*)d_in[2];
  float* out = (float*)d_out;

  const int Bv = in_sizes[1];            // 1024
  const int Dv = in_sizes[0] / Bv;       // 256
  const int Nn = in_sizes[2] / Dv;       // 100000

  u16* xb = (u16*)d_ws;                                         // bf16 x: B*D
  const size_t x_bytes = ((size_t)Bv * Dv * 2 + 255) & ~(size_t)255;
  u16* fb = (u16*)((char*)d_ws + x_bytes);                      // bf16 features: N*D
  const size_t f_bytes = (size_t)Nn * Dv * 2;
  const bool fits = ws_size >= x_bytes + f_bytes;

  norm_cast_kernel<<<dim3(Bv), dim3(256), 0, stream>>>(inputs, xb);

  dim3 grid(Bv / 128, (Nn + 127) / 128);
  if (fits) {
    const int n4 = (Nn * Dv) / 4;
    cvt_bf16_kernel<<<dim3((n4 + 255) / 256), dim3(256), 0, stream>>>(
        (const float4*)features, (ushort4*)fb, n4);
    gemm_kernel<false><<<grid, dim3(256), 0, stream>>>(xb, fb, nullptr, out, Nn);
  } else {
    gemm_kernel<true><<<grid, dim3(256), 0, stream>>>(xb, nullptr, features, out, Nn);
  }
}